// Round 11
// baseline (318.798 us; speedup 1.0000x reference)
//
#include <hip/hip_runtime.h>

// GAE backward linear recurrence — per-instruction fully-contiguous layout.
// One wave per row (B=8192, T=2048). Row = NBLK=8 blocks of SEG=256; lane
// owns PER_LANE=4 CONSECUTIVE timesteps. Every global load/store instruction
// is one contiguous 1 KB wave-span (lane i at base + i*16B -> 8 cache lines
// per instruction, 100% line density — matches the 6.3 TB/s copy ubench
// pattern). Scan: per-block affine compose -> 8 independent 64-lane
// Kogge-Stone suffix chains -> register-only cross-block carry -> rescan.

constexpr float GAMMA_F = 0.99f;
constexpr float GL      = 0.99f * 0.95f;
constexpr int   T_LEN   = 2048;
constexpr int   PER_LANE = 4;
constexpr int   SEG     = 64 * PER_LANE;   // 256
constexpr int   NBLK    = T_LEN / SEG;     // 8
constexpr int   WPB     = 4;               // waves per block (256 threads)

constexpr float gl_pow4() {
    double p = 1.0;
    for (int i = 0; i < 4; ++i) p *= (double)GL;
    return (float)p;
}
constexpr float GL4 = gl_pow4();

__global__ __launch_bounds__(256)
void gae_kernel(const float* __restrict__ reward,
                const int*   __restrict__ term,
                const float* __restrict__ value,
                const float* __restrict__ next_value,
                float* __restrict__ adv_out,
                float* __restrict__ ret_out,
                int rows) {
    const int wid  = threadIdx.x >> 6;
    const int lane = threadIdx.x & 63;
    const int row  = blockIdx.x * WPB + wid;
    if (row >= rows) return;

    const long rowbase = (long)row * T_LEN;
    const long lanoff  = lane * PER_LANE;

    // ---- phase 0: issue loads (independent; each instr = contiguous 1 KB) ----
    float4 rr4[NBLK], vv4[NBLK], nn4[NBLK];
    int4   tt4[NBLK];
#pragma unroll
    for (int b = 0; b < NBLK; ++b) {
        const long base = rowbase + (long)b * SEG + lanoff;
        rr4[b] = *reinterpret_cast<const float4*>(reward + base);
        tt4[b] = *reinterpret_cast<const int4*>(term + base);
        vv4[b] = *reinterpret_cast<const float4*>(value + base);
        nn4[b] = *reinterpret_cast<const float4*>(next_value + base);
    }

    // ---- phase 1: per-block delta + local 4-elem suffix compose ----
    float    d[NBLK][PER_LANE], vv[NBLK][PER_LANE];
    unsigned mask[NBLK];
    float    A[NBLK], Bc[NBLK];
#pragma unroll
    for (int b = 0; b < NBLK; ++b) {
        const float rr[4]  = {rr4[b].x, rr4[b].y, rr4[b].z, rr4[b].w};
        const int   tt[4]  = {tt4[b].x, tt4[b].y, tt4[b].z, tt4[b].w};
        const float vvl[4] = {vv4[b].x, vv4[b].y, vv4[b].z, vv4[b].w};
        const float nn[4]  = {nn4[b].x, nn4[b].y, nn4[b].z, nn4[b].w};
        unsigned m = 0;
#pragma unroll
        for (int j = 0; j < PER_LANE; ++j) {
            const float nd = (float)(1 - tt[j]);
            d[b][j]  = fmaf(GAMMA_F * nd, nn[j], rr[j]) - vvl[j];
            vv[b][j] = vvl[j];
            m |= (tt[j] ? 0u : 1u) << j;
        }
        mask[b] = m;
        float bc = 0.0f;
#pragma unroll
        for (int j = PER_LANE - 1; j >= 0; --j) {
            const float a = ((m >> j) & 1u) ? GL : 0.0f;
            bc = fmaf(a, bc, d[b][j]);
        }
        Bc[b] = bc;
        A[b]  = (m == 0xFu) ? GL4 : 0.0f;
    }

    // ---- phase 2: Kogge-Stone suffix compose, 8 independent chains ----
#pragma unroll
    for (int off = 1; off < 64; off <<= 1) {
#pragma unroll
        for (int b = 0; b < NBLK; ++b) {
            const float A2 = __shfl_down(A[b], off, 64);
            const float B2 = __shfl_down(Bc[b], off, 64);
            if (lane + off < 64) {
                Bc[b] = fmaf(A[b], B2, Bc[b]);   // uses old A
                A[b] *= A2;
            }
        }
    }

    float As1[NBLK], Bs1[NBLK], A0[NBLK], B0[NBLK];
#pragma unroll
    for (int b = 0; b < NBLK; ++b) {
        As1[b] = __shfl_down(A[b], 1, 64);
        Bs1[b] = __shfl_down(Bc[b], 1, 64);
        A0[b]  = __shfl(A[b], 0, 64);
        B0[b]  = __shfl(Bc[b], 0, 64);
    }

    // ---- phase 3: cross-block carries (block NBLK-1 latest in time) ----
    float carry[NBLK];
    carry[NBLK - 1] = 0.0f;
#pragma unroll
    for (int b = NBLK - 2; b >= 0; --b)
        carry[b] = fmaf(A0[b + 1], carry[b + 1], B0[b + 1]);

    // ---- phase 4: rescan with true carry, contiguous stores ----
#pragma unroll
    for (int b = 0; b < NBLK; ++b) {
        float g = (lane == 63) ? carry[b] : fmaf(As1[b], carry[b], Bs1[b]);
        float ga[4], ro[4];
#pragma unroll
        for (int j = PER_LANE - 1; j >= 0; --j) {
            const float a = ((mask[b] >> j) & 1u) ? GL : 0.0f;
            g = fmaf(a, g, d[b][j]);
            ga[j] = g;
            ro[j] = g + vv[b][j];
        }
        const long ob = rowbase + (long)b * SEG + lanoff;
        *reinterpret_cast<float4*>(adv_out + ob) = make_float4(ga[0], ga[1], ga[2], ga[3]);
        *reinterpret_cast<float4*>(ret_out + ob) = make_float4(ro[0], ro[1], ro[2], ro[3]);
    }
}

extern "C" void kernel_launch(void* const* d_in, const int* in_sizes, int n_in,
                              void* d_out, int out_size, void* d_ws, size_t ws_size,
                              hipStream_t stream) {
    const float* reward     = (const float*)d_in[0];
    const int*   terminated = (const int*)d_in[1];
    const float* value      = (const float*)d_in[2];
    const float* next_value = (const float*)d_in[3];

    const int total = in_sizes[0];     // B * T
    const int rows  = total / T_LEN;   // B

    float* adv = (float*)d_out;
    float* ret = adv + (long)total;

    const int block = 64 * WPB;
    const int grid  = (rows + WPB - 1) / WPB;
    gae_kernel<<<grid, block, 0, stream>>>(reward, terminated, value, next_value,
                                           adv, ret, rows);
}